// Round 7
// baseline (330.998 us; speedup 1.0000x reference)
//
#include <hip/hip_runtime.h>
#include <hip/hip_bf16.h>

// Swin window self-attention, fused. R12: R11 with the c-tile buffer
// de-address-ized (single-variable experiment).
//  - R11 theory: gatherC(qt, f32x4* c) pointer out-param defeated SROA ->
//    c[2][4] demoted to scratch -> ~3 MB/XCD of hot dirty scratch lines
//    thrashing L2 -> WRITE 100->207 MB, FETCH 70->125 MB, dur 148->180.
//  - Fix: gatherC returns a c4 struct BY VALUE; double-buffer is two named
//    structs (cA/cB) selected at compile time inside the unrolled qt loop.
//    No array anywhere has its address taken.
//  - Everything else identical to R11: one block per window (4096 blocks),
//    wave = head, permuted-k MFMA (0 shuffles outside softmax, 0 LDS),
//    X register-resident, mask+bias as QK^T C-operand (pad=-30000 masks
//    n>=49), max-free softmax, fused per-qt softmax->PV, swapped-PV float4
//    stores, pre-store __syncthreads for L2 write-merge.

#define SEQ 49
#define CH 128
#define NH 4
#define DHD 32
#define NTAB 169

typedef __hip_bfloat16 bf16;
typedef __attribute__((ext_vector_type(8))) short bf16x8;  // 8 bf16 = 4 VGPRs
typedef __attribute__((ext_vector_type(4))) float f32x4;
typedef float f32x4a __attribute__((ext_vector_type(4), aligned(4)));  // 4B-ok

#define WP_FRAGS (3*NH*2*4*64)           // 6144 frags of 8 bf16
#define WP_BYTES (WP_FRAGS*8*2)          // 98304
#define BIAS_ELEMS (NH*64*64)            // 16384
#define BIAS_BYTES (BIAS_ELEMS*4)        // 65536
#define WS_NEED ((size_t)(WP_BYTES + BIAS_BYTES))  // 163840

__device__ __forceinline__ bf16x8 pack8(float4 a, float4 b) {
    alignas(16) bf16 t[8] = {
        __float2bfloat16(a.x), __float2bfloat16(a.y),
        __float2bfloat16(a.z), __float2bfloat16(a.w),
        __float2bfloat16(b.x), __float2bfloat16(b.y),
        __float2bfloat16(b.z), __float2bfloat16(b.w)};
    return *(const bf16x8*)t;
}

__device__ __forceinline__ unsigned pk2(float lo, float hi) {
    union { bf16 h[2]; unsigned u; } r;
    r.h[0] = __float2bfloat16(lo);
    r.h[1] = __float2bfloat16(hi);
    return r.u;
}

union frag_u { unsigned u[4]; bf16x8 v; };
struct c4 { f32x4 c0, c1, c2, c3; };     // one qt-tile of mask+bias (C-op)

// Pre-pass: pack W{q,k,v} into per-head bf16 frags wp[which][h][t][ks][lane][8]
// = W[h*32 + 16t + (lane&15)][32ks + (lane>>4)*8 + jj]; and gather the
// rel-pos bias m-major: bias_m[h][m 64][n 64], padding = -30000 (acts as the
// n>=SEQ mask directly in the QK^T C-operand).
__global__ void prep_kernel(const float* __restrict__ Wq,
                            const float* __restrict__ Wk,
                            const float* __restrict__ Wv,
                            const float* __restrict__ table,
                            const int*  __restrict__ ridx,
                            bf16* __restrict__ wp,
                            float* __restrict__ bias_m) {
    int i = blockIdx.x*256 + threadIdx.x;
    if (i < WP_FRAGS) {
        int lane = i & 63, ks = (i >> 6) & 3, t = (i >> 8) & 1;
        int h = (i >> 9) & 3, which = i >> 11;
        const float* W = which == 0 ? Wq : (which == 1 ? Wk : Wv);
        const float* p = W + (h*DHD + t*16 + (lane & 15))*CH + ks*32 + (lane >> 4)*8;
        ((bf16x8*)wp)[i] = pack8(*(const float4*)p, *(const float4*)(p + 4));
    } else {
        int j = i - WP_FRAGS;
        if (j < BIAS_ELEMS) {
            int h = j >> 12, m = (j >> 6) & 63, n = j & 63;
            float v = -30000.f;
            if (m < SEQ && n < SEQ) {
                int idx = ridx[m*SEQ + n];
                idx = idx < 0 ? 0 : (idx > NTAB-1 ? NTAB-1 : idx);
                v = table[idx*NH + h];
            }
            bias_m[j] = v;
        }
    }
}

template<bool WS>
__global__ __launch_bounds__(256, 3) void swin_attn_kernel(
    const float* __restrict__ hs,     // [B,49,128]
    const float* __restrict__ amask,  // [B,49,49]
    const float* __restrict__ Wq, const float* __restrict__ bq,
    const float* __restrict__ Wk, const float* __restrict__ bk,
    const float* __restrict__ Wv, const float* __restrict__ bv,
    const float* __restrict__ table,  // [169,4]
    const int*  __restrict__ ridx,    // [2401]
    const bf16*  __restrict__ wp,     // packed W frags (WS)
    const float* __restrict__ bias_m, // [4][64 m][64 n], pad=-30000 (WS)
    float* __restrict__ out)          // [B,49,128]
{
    const int w = blockIdx.x;
    const int h = threadIdx.x >> 6;   // wave = head
    const int lane = threadIdx.x & 63;
    const int l = lane & 15;
    const int q = lane >> 4;
    const f32x4 z4 = {0.f, 0.f, 0.f, 0.f};

    auto loadW = [&](int which, int t, int ks) -> bf16x8 {
        if (WS) {
            return *(const bf16x8*)(wp +
                ((((size_t)(which*NH + h)*2 + t)*4 + ks)*64 + lane)*8);
        } else {
            const float* W = which == 0 ? Wq : (which == 1 ? Wk : Wv);
            const float* p = W + (h*DHD + t*16 + l)*CH + ks*32 + q*8;
            return pack8(*(const float4*)p, *(const float4*)(p + 4));
        }
    };
    const float* biash = WS ? bias_m + h*4096 : nullptr;
    const float* xb    = hs + (size_t)w*SEQ*CH;
    const float* maskb = amask + (size_t)w*SEQ*SEQ;

    // ---- X loaded once, resident (16 frags = 64 VGPR); rows clamped to 48
    // (row>=49 garbage harmless: never stored / P=0 via bias pad).
    // X frag: X[16rt + l][32ks + 8q + jj].
    bf16x8 xf[4][4];
#pragma unroll
    for (int rt = 0; rt < 4; ++rt) {
        int row = rt*16 + l; row = row > SEQ-1 ? SEQ-1 : row;
        const float* xr = xb + row*CH + q*8;
#pragma unroll
        for (int ks = 0; ks < 4; ++ks)
            xf[rt][ks] = pack8(*(const float4*)(xr + ks*32),
                               *(const float4*)(xr + ks*32 + 4));
    }

    // ---- c-gather (BY VALUE): c = mask[m][n] + bias[m][n] at the exact S^T
    // D-layout (n = 16kt+4q+r, m = 16qt+l). kt=3: only n=48 is real (scalar
    // load on q==0 lanes); the rest comes from bias pad = -30000.
    auto gatherC = [&](int qt) -> c4 {
        const int m = qt*16 + l;
        const int mc = m > SEQ-1 ? SEQ-1 : m;
        const float* mr = maskb + (size_t)mc*SEQ;
        f32x4 p0 = *(const f32x4a*)(mr + 4*q);
        f32x4 p1 = *(const f32x4a*)(mr + 16 + 4*q);
        f32x4 p2 = *(const f32x4a*)(mr + 32 + 4*q);
        f32x4 p3 = z4;
        if (q == 0) p3[0] = mr[48];
        if (WS) {
            const float* br = biash + m*64 + 4*q;
            c4 r;
            r.c0 = p0 + *(const f32x4a*)(br);
            r.c1 = p1 + *(const f32x4a*)(br + 16);
            r.c2 = p2 + *(const f32x4a*)(br + 32);
            r.c3 = p3 + *(const f32x4a*)(br + 48);
            return r;
        } else {
            f32x4 b0 = z4, b1 = z4, b2 = z4, b3 = z4;
#pragma unroll
            for (int r = 0; r < 4; ++r) {
                const int n0 = 4*q + r;
                int i0 = ridx[mc*SEQ + n0];
                i0 = i0 < 0 ? 0 : (i0 > NTAB-1 ? NTAB-1 : i0);
                b0[r] = table[i0*NH + h];
                int i1 = ridx[mc*SEQ + 16 + n0];
                i1 = i1 < 0 ? 0 : (i1 > NTAB-1 ? NTAB-1 : i1);
                b1[r] = table[i1*NH + h];
                int i2 = ridx[mc*SEQ + 32 + n0];
                i2 = i2 < 0 ? 0 : (i2 > NTAB-1 ? NTAB-1 : i2);
                b2[r] = table[i2*NH + h];
                if (48 + n0 < SEQ) {
                    int i3 = ridx[mc*SEQ + 48 + n0];
                    i3 = i3 < 0 ? 0 : (i3 > NTAB-1 ? NTAB-1 : i3);
                    b3[r] = table[i3*NH + h];
                } else {
                    b3[r] = -30000.f;
                }
            }
            c4 r;
            r.c0 = p0 + b0; r.c1 = p1 + b1; r.c2 = p2 + b2; r.c3 = p3 + b3;
            return r;
        }
    };

    // ---- V projection (A=X, B=W), dt-split, from resident X.
    // D lane (q,l) = V[n = 16nt+4q+r][d = 16dt+l] -> permuted-k B-frag
    // uV[dt][ks2] slot (q,jj) = V[32ks2 + 16(jj>>2) + 4q + (jj&3)][16dt+l].
    frag_u uV[2][2];
#pragma unroll
    for (int dt = 0; dt < 2; ++dt) {
        f32x4 acc[4] = {z4, z4, z4, z4};
#pragma unroll
        for (int ks = 0; ks < 4; ++ks) {
            const bf16x8 wf = loadW(2, dt, ks);
#pragma unroll
            for (int nt = 0; nt < 4; ++nt)
                acc[nt] = __builtin_amdgcn_mfma_f32_16x16x32_bf16(
                    xf[nt][ks], wf, acc[nt], 0, 0, 0);
        }
#pragma unroll
        for (int ks2 = 0; ks2 < 2; ++ks2) {
            uV[dt][ks2].u[0] = pk2(acc[2*ks2][0],   acc[2*ks2][1]);
            uV[dt][ks2].u[1] = pk2(acc[2*ks2][2],   acc[2*ks2][3]);
            uV[dt][ks2].u[2] = pk2(acc[2*ks2+1][0], acc[2*ks2+1][1]);
            uV[dt][ks2].u[3] = pk2(acc[2*ks2+1][2], acc[2*ks2+1][3]);
        }
    }

    // first c tile in flight under the QK projections
    c4 cA = gatherC(0);
    c4 cB{};

    // ---- Q^T / K^T projections (A=W, B=X), t-split; packed DIRECTLY as
    // permuted-k frag words (slot (q,jj) <-> channel 16(jj>>2)+4q+(jj&3)).
    frag_u uQ[4], uK[4];
#pragma unroll
    for (int which = 0; which < 2; ++which) {
        const float* bvec = which == 0 ? bq : bk;
        const float sc = which == 0 ? 0.17677669529663687f : 1.0f; // 1/sqrt(32)
#pragma unroll
        for (int t = 0; t < 2; ++t) {
            f32x4 acc[4] = {z4, z4, z4, z4};
#pragma unroll
            for (int ks = 0; ks < 4; ++ks) {
                const bf16x8 wf = loadW(which, t, ks);
#pragma unroll
                for (int rt = 0; rt < 4; ++rt)
                    acc[rt] = __builtin_amdgcn_mfma_f32_16x16x32_bf16(
                        wf, xf[rt][ks], acc[rt], 0, 0, 0);
            }
            const float b0 = bvec[h*DHD + t*16 + 4*q + 0];
            const float b1 = bvec[h*DHD + t*16 + 4*q + 1];
            const float b2 = bvec[h*DHD + t*16 + 4*q + 2];
            const float b3 = bvec[h*DHD + t*16 + 4*q + 3];
#pragma unroll
            for (int rt = 0; rt < 4; ++rt) {
                const unsigned w0 = pk2((acc[rt][0]+b0)*sc, (acc[rt][1]+b1)*sc);
                const unsigned w1 = pk2((acc[rt][2]+b2)*sc, (acc[rt][3]+b3)*sc);
                if (which == 0) { uQ[rt].u[2*t] = w0; uQ[rt].u[2*t+1] = w1; }
                else            { uK[rt].u[2*t] = w0; uK[rt].u[2*t+1] = w1; }
            }
        }
    }
    // xf dead past this point

    // ---- fused S -> softmax -> PV, per qt. cA/cB double-buffer selected at
    // compile time (loop fully unrolled); prefetch one qt ahead.
    // S^T[n = 16kt+4q+r][m = 16qt+l] = K.Q^T + (mask+bias) via C-operand.
    // No max-subtraction (scores bounded; ratio identical). Padded n: bias
    // -30000 -> exp==0. Padded m rows: sum==0 -> NaN, confined to output
    // columns never stored.
    f32x4 O[2][4] = {{z4,z4,z4,z4},{z4,z4,z4,z4}};   // [dt][qt]
#pragma unroll
    for (int qt = 0; qt < 4; ++qt) {
        const c4 cc = (qt & 1) ? cB : cA;
        if (qt == 0)      cB = gatherC(1);
        else if (qt == 1) cA = gatherC(2);
        else if (qt == 2) cB = gatherC(3);
        f32x4 s4[4];
        __builtin_amdgcn_s_setprio(1);
        s4[0] = __builtin_amdgcn_mfma_f32_16x16x32_bf16(uK[0].v, uQ[qt].v, cc.c0, 0, 0, 0);
        s4[1] = __builtin_amdgcn_mfma_f32_16x16x32_bf16(uK[1].v, uQ[qt].v, cc.c1, 0, 0, 0);
        s4[2] = __builtin_amdgcn_mfma_f32_16x16x32_bf16(uK[2].v, uQ[qt].v, cc.c2, 0, 0, 0);
        s4[3] = __builtin_amdgcn_mfma_f32_16x16x32_bf16(uK[3].v, uQ[qt].v, cc.c3, 0, 0, 0);
        __builtin_amdgcn_s_setprio(0);
        float sum = 0.f;
#pragma unroll
        for (int kt = 0; kt < 4; ++kt)
#pragma unroll
            for (int r = 0; r < 4; ++r) {
                const float e = __expf(s4[kt][r]);
                s4[kt][r] = e;
                sum += e;
            }
        sum += __shfl_xor(sum, 16);
        sum += __shfl_xor(sum, 32);
        const float inv = 1.f / sum;
        unsigned pk_[4][2];
#pragma unroll
        for (int kt = 0; kt < 4; ++kt) {
            pk_[kt][0] = pk2(s4[kt][0]*inv, s4[kt][1]*inv);
            pk_[kt][1] = pk2(s4[kt][2]*inv, s4[kt][3]*inv);
        }
        __builtin_amdgcn_s_setprio(1);
#pragma unroll
        for (int ks2 = 0; ks2 < 2; ++ks2) {
            frag_u a;
            a.u[0] = pk_[2*ks2][0];
            a.u[1] = pk_[2*ks2][1];
            a.u[2] = pk_[2*ks2+1][0];
            a.u[3] = pk_[2*ks2+1][1];
#pragma unroll
            for (int dt = 0; dt < 2; ++dt)
                O[dt][qt] = __builtin_amdgcn_mfma_f32_16x16x32_bf16(
                    uV[dt][ks2].v, a.v, O[dt][qt], 0, 0, 0);
        }
        __builtin_amdgcn_s_setprio(0);
    }

    // Re-converge the 4 waves before storing (write-merge in L2), then
    // 8 float4 stores: lane (q,l) writes out[m=16qt+l][h*32+16dt+4q..+3].
    const float* bvh = bv + h*DHD;
    const f32x4 bva0 = *(const f32x4*)(bvh + 4*q);
    const f32x4 bva1 = *(const f32x4*)(bvh + 16 + 4*q);
    __syncthreads();
    float* ob = out + (size_t)w*SEQ*CH + h*DHD;
#pragma unroll
    for (int qt = 0; qt < 4; ++qt) {
        const int m = qt*16 + l;
        if (m < SEQ) {
            *(f32x4*)(ob + (size_t)m*CH + 4*q)      = O[0][qt] + bva0;
            *(f32x4*)(ob + (size_t)m*CH + 16 + 4*q) = O[1][qt] + bva1;
        }
    }
}

extern "C" void kernel_launch(void* const* d_in, const int* in_sizes, int n_in,
                              void* d_out, int out_size, void* d_ws, size_t ws_size,
                              hipStream_t stream) {
    (void)n_in; (void)out_size;
    const int nwin = in_sizes[0] / (SEQ * CH);
    const bool usews = (d_ws != nullptr) && (ws_size >= WS_NEED);
    if (usews) {
        bf16* wp = (bf16*)d_ws;
        float* bias_m = (float*)((char*)d_ws + WP_BYTES);
        prep_kernel<<<dim3((WP_FRAGS + BIAS_ELEMS + 255)/256), dim3(256), 0, stream>>>(
            (const float*)d_in[2], (const float*)d_in[4], (const float*)d_in[6],
            (const float*)d_in[8], (const int*)d_in[9], wp, bias_m);
        swin_attn_kernel<true><<<dim3(nwin), dim3(256), 0, stream>>>(
            (const float*)d_in[0], (const float*)d_in[1],
            (const float*)d_in[2], (const float*)d_in[3],
            (const float*)d_in[4], (const float*)d_in[5],
            (const float*)d_in[6], (const float*)d_in[7],
            (const float*)d_in[8], (const int*)d_in[9],
            wp, bias_m, (float*)d_out);
    } else {
        swin_attn_kernel<false><<<dim3(nwin), dim3(256), 0, stream>>>(
            (const float*)d_in[0], (const float*)d_in[1],
            (const float*)d_in[2], (const float*)d_in[3],
            (const float*)d_in[4], (const float*)d_in[5],
            (const float*)d_in[6], (const float*)d_in[7],
            (const float*)d_in[8], (const int*)d_in[9],
            nullptr, nullptr, (float*)d_out);
    }
}